// Round 2
// baseline (842.803 us; speedup 1.0000x reference)
//
#include <hip/hip_runtime.h>
#include <hip/hip_bf16.h>

// Problem constants
#define NPIX   16384      // 128*128
#define NRROWS 2048       // r rows
#define NLROWS 5120       // l rows (= GEMM K)
#define NVROWS 4096       // v rows (= GEMM M)
#define GK     5120
#define BK8    64         // GEMM K-step
#define NT     (GK / BK8) // 80

using f32x4    = __attribute__((ext_vector_type(4))) float;
using bf16x8   = __attribute__((ext_vector_type(8))) __bf16;
using ushortx8 = __attribute__((ext_vector_type(8))) unsigned short;

// fp32 -> bf16 round-to-nearest-even (no NaN inputs in this problem)
__device__ __forceinline__ unsigned short f2b(float f) {
    union { float f; unsigned u; } v; v.f = f;
    unsigned r = (v.u + 0x7FFFu + ((v.u >> 16) & 1u)) >> 16;
    return (unsigned short)r;
}

#define GLOAD_LDS16(gsrc, ldst)                                                        \
    __builtin_amdgcn_global_load_lds(                                                  \
        (const __attribute__((address_space(1))) void*)(gsrc),                         \
        (__attribute__((address_space(3))) void*)(ldst), 16, 0, 0)

// ---------------- Fused stages 1+2: r, l = [r ; r[lgn_idx]], lbt = bf16(l)^T --------
// lgn_idx only indexes [0, 2048), so every l-row is recomputable directly from
// x/act_on/act_off (bit-exact vs computing r then gathering).
__global__ __launch_bounds__(256) void lgn_fused_kernel(const float* __restrict__ x,
                                                        const float* __restrict__ act_on,
                                                        const float* __restrict__ act_off,
                                                        const int* __restrict__ lgn_idx,
                                                        float* __restrict__ r,
                                                        float* __restrict__ l,
                                                        unsigned short* __restrict__ lbt) {
    __shared__ unsigned short tile[64][66];
    const int k0 = blockIdx.y * 64;     // l-row tile base
    const int n0 = blockIdx.x * 64;     // pixel tile base
    const int t  = threadIdx.x;
    #pragma unroll
    for (int p = 0; p < 4; ++p) {
        int row = p * 16 + (t >> 4);
        int kk  = k0 + row;
        int src = (kk < NRROWS) ? kk : lgn_idx[kk - NRROWS];
        int c4  = t & 15;
        int px  = n0 + c4 * 4;
        float4 xv = *reinterpret_cast<const float4*>(&x[px]);
        float4 d;
        if (src < 1024) {
            float4 a = *reinterpret_cast<const float4*>(&act_on[(size_t)src * NPIX + px]);
            d.x = xv.x * a.x; d.y = xv.y * a.y; d.z = xv.z * a.z; d.w = xv.w * a.w;
        } else {
            float4 a = *reinterpret_cast<const float4*>(&act_off[(size_t)(src - 1024) * NPIX + px]);
            d.x = (1.f - xv.x) * a.x; d.y = (1.f - xv.y) * a.y;
            d.z = (1.f - xv.z) * a.z; d.w = (1.f - xv.w) * a.w;
        }
        *reinterpret_cast<float4*>(&l[(size_t)kk * NPIX + px]) = d;
        if (kk < NRROWS)
            *reinterpret_cast<float4*>(&r[(size_t)kk * NPIX + px]) = d;
        tile[row][c4 * 4 + 0] = f2b(d.x);
        tile[row][c4 * 4 + 1] = f2b(d.y);
        tile[row][c4 * 4 + 2] = f2b(d.z);
        tile[row][c4 * 4 + 3] = f2b(d.w);
    }
    __syncthreads();
    #pragma unroll
    for (int p = 0; p < 4; ++p) {
        int nn = p * 16 + (t >> 4);     // output row (= pixel)
        int k4 = t & 15;
        ushort4 s;
        s.x = tile[k4 * 4 + 0][nn];
        s.y = tile[k4 * 4 + 1][nn];
        s.z = tile[k4 * 4 + 2][nn];
        s.w = tile[k4 * 4 + 3][nn];
        *reinterpret_cast<ushort4*>(&lbt[(size_t)(n0 + nn) * GK + k0 + k4 * 4]) = s;
    }
}

// ---------------- conn fp32 -> bf16 ----------------
__global__ __launch_bounds__(256) void cvt_conn_kernel(const float* __restrict__ A,
                                                       unsigned short* __restrict__ Ab) {
    unsigned f = blockIdx.x * 256u + threadIdx.x;
    float4 d = reinterpret_cast<const float4*>(A)[f];
    ushort4 s;
    s.x = f2b(d.x); s.y = f2b(d.y); s.z = f2b(d.z); s.w = f2b(d.w);
    reinterpret_cast<ushort4*>(Ab)[f] = s;
}

// ---------------- Stage 3: v = conn @ l — 256x256, BK=64, single-sync schedule ----
// One sync point per K-tile: all 8 global_load_lds for tile t+1 are issued spread
// through tile t (full-tile ~2300cyc prefetch distance >> DMA latency), then a
// single vmcnt(0)+s_barrier at tile end publishes buf[nxt] for everyone.
// No mid-tile barriers / manual lgkmcnt: the compiler emits counted lgkmcnt
// between each ds_read and its consuming MFMA, so reads and MFMAs interleave
// across the whole tile (LDS pipe || MFMA pipe), and waves drift freely between
// the per-tile barriers.
// Correctness: every ds_read of buf[cur] feeds an MFMA that precedes the barrier
// (lgkm drained by use), and stages only touch buf[nxt] -> the single barrier is
// sufficient.
__global__ __launch_bounds__(512, 2) void gemm8_kernel(const unsigned short* __restrict__ Ab, // conn bf16 [4096][5120]
                                                       const unsigned short* __restrict__ Bb, // lbt [16384][5120]
                                                       float* __restrict__ C) {               // v [4096][16384]
    __shared__ unsigned short lds[2][2][256][64];   // [buf][A=0/B=1][row][col]

    const int tid  = threadIdx.x;
    const int lane = tid & 63;
    const int wid  = tid >> 6;
    const int wm   = wid >> 2;       // 0..1 : 64-row sub-block within each 128-quadrant
    const int wn   = wid & 3;        // 0..3 : 32-col sub-block within each 128-quadrant

    // XCD-aware bijective swizzle: 1024 wg, 8 XCDs, m-fast within XCD chunk.
    int bid = blockIdx.x;
    int swz = (bid & 7) * 128 + (bid >> 3);
    int mb  = swz & 15;
    int nb  = swz >> 4;
    const int row0 = mb * 256;
    const int col0 = nb * 256;

    // staging: STAGE(buf, rnd, kt) covers rows rnd*64 + (tid>>3); lane loads source
    // chunk gc = (lane&7) ^ (lane>>3)  (pre-swizzled global source; LDS dest linear)
    const int strow = tid >> 3;                 // 0..63
    const int gc    = (lane & 7) ^ (lane >> 3);

#define STAGE_A(buf, rnd, kt)                                                          \
    GLOAD_LDS16(&Ab[(size_t)(row0 + (rnd) * 64 + strow) * GK + (kt) * BK8 + gc * 8],   \
                &lds[buf][0][(rnd) * 64 + strow][(lane & 7) * 8])
#define STAGE_B(buf, rnd, kt)                                                          \
    GLOAD_LDS16(&Bb[(size_t)(col0 + (rnd) * 64 + strow) * GK + (kt) * BK8 + gc * 8],   \
                &lds[buf][1][(rnd) * 64 + strow][(lane & 7) * 8])

// swizzled fragment read: global chunk c of row lives at LDS chunk c^(row&7)
#define FRAG(buf, op, row, c)                                                          \
    __builtin_bit_cast(bf16x8, *reinterpret_cast<const ushortx8*>(                     \
        &lds[buf][op][row][(((c) ^ ((row) & 7)) * 8)]))

    f32x4 acc[2][2][4][2] = {};      // [qm][qn][m][n]
    const int fr = lane & 15;
    const int kg = lane >> 4;        // k-group: chunk = ks*4 + kg

    bf16x8 af[2][4][2];              // both A halves stay in registers
    bf16x8 b[2][2];                  // current B half

    // prologue: tile 0 -> buf 0
    STAGE_A(0, 0, 0); STAGE_A(0, 1, 0);
    STAGE_B(0, 0, 0); STAGE_B(0, 1, 0);
    STAGE_A(0, 2, 0); STAGE_A(0, 3, 0);
    STAGE_B(0, 2, 0); STAGE_B(0, 3, 0);
    asm volatile("s_waitcnt vmcnt(0)" ::: "memory");   // tile 0 landed
    __builtin_amdgcn_s_barrier();

    for (int t = 0; t < NT - 1; ++t) {
        const int cur = t & 1;
        const int nxt = cur ^ 1;

        // ---- cluster 0: Q(0,0) — A0, B-low ----
        #pragma unroll
        for (int n = 0; n < 2; ++n)
            #pragma unroll
            for (int ks = 0; ks < 2; ++ks)
                b[n][ks] = FRAG(cur, 1, wn * 32 + n * 16 + fr, ks * 4 + kg);
        #pragma unroll
        for (int m = 0; m < 4; ++m)
            #pragma unroll
            for (int ks = 0; ks < 2; ++ks)
                af[0][m][ks] = FRAG(cur, 0, wm * 64 + m * 16 + fr, ks * 4 + kg);
        STAGE_A(nxt, 0, t + 1); STAGE_A(nxt, 1, t + 1);
        __builtin_amdgcn_s_setprio(1);
        #pragma unroll
        for (int m = 0; m < 4; ++m)
            #pragma unroll
            for (int n = 0; n < 2; ++n)
                #pragma unroll
                for (int ks = 0; ks < 2; ++ks)
                    acc[0][0][m][n] = __builtin_amdgcn_mfma_f32_16x16x32_bf16(af[0][m][ks], b[n][ks], acc[0][0][m][n], 0, 0, 0);
        __builtin_amdgcn_s_setprio(0);

        // ---- cluster 1: Q(1,0) — A1, B-low (regs) ----
        #pragma unroll
        for (int m = 0; m < 4; ++m)
            #pragma unroll
            for (int ks = 0; ks < 2; ++ks)
                af[1][m][ks] = FRAG(cur, 0, 128 + wm * 64 + m * 16 + fr, ks * 4 + kg);
        STAGE_B(nxt, 0, t + 1); STAGE_B(nxt, 1, t + 1);
        __builtin_amdgcn_s_setprio(1);
        #pragma unroll
        for (int m = 0; m < 4; ++m)
            #pragma unroll
            for (int n = 0; n < 2; ++n)
                #pragma unroll
                for (int ks = 0; ks < 2; ++ks)
                    acc[1][0][m][n] = __builtin_amdgcn_mfma_f32_16x16x32_bf16(af[1][m][ks], b[n][ks], acc[1][0][m][n], 0, 0, 0);
        __builtin_amdgcn_s_setprio(0);

        // ---- cluster 2: Q(1,1) — A1 (regs), B-high ----
        #pragma unroll
        for (int n = 0; n < 2; ++n)
            #pragma unroll
            for (int ks = 0; ks < 2; ++ks)
                b[n][ks] = FRAG(cur, 1, 128 + wn * 32 + n * 16 + fr, ks * 4 + kg);
        STAGE_A(nxt, 2, t + 1); STAGE_A(nxt, 3, t + 1);
        __builtin_amdgcn_s_setprio(1);
        #pragma unroll
        for (int m = 0; m < 4; ++m)
            #pragma unroll
            for (int n = 0; n < 2; ++n)
                #pragma unroll
                for (int ks = 0; ks < 2; ++ks)
                    acc[1][1][m][n] = __builtin_amdgcn_mfma_f32_16x16x32_bf16(af[1][m][ks], b[n][ks], acc[1][1][m][n], 0, 0, 0);
        __builtin_amdgcn_s_setprio(0);

        // ---- cluster 3: Q(0,1) — A0 (regs), B-high (regs) ----
        STAGE_B(nxt, 2, t + 1); STAGE_B(nxt, 3, t + 1);
        __builtin_amdgcn_s_setprio(1);
        #pragma unroll
        for (int m = 0; m < 4; ++m)
            #pragma unroll
            for (int n = 0; n < 2; ++n)
                #pragma unroll
                for (int ks = 0; ks < 2; ++ks)
                    acc[0][1][m][n] = __builtin_amdgcn_mfma_f32_16x16x32_bf16(af[0][m][ks], b[n][ks], acc[0][1][m][n], 0, 0, 0);
        __builtin_amdgcn_s_setprio(0);

        // ---- single sync point: tile t+1 published ----
        asm volatile("s_waitcnt vmcnt(0)" ::: "memory");
        __builtin_amdgcn_s_barrier();
    }

    // ======== epilogue tile NT-1 (no staging, no barriers) ========
    {
        const int cur = (NT - 1) & 1;
        #pragma unroll
        for (int m = 0; m < 4; ++m)
            #pragma unroll
            for (int ks = 0; ks < 2; ++ks) {
                af[0][m][ks] = FRAG(cur, 0, wm * 64 + m * 16 + fr, ks * 4 + kg);
                af[1][m][ks] = FRAG(cur, 0, 128 + wm * 64 + m * 16 + fr, ks * 4 + kg);
            }
        #pragma unroll
        for (int n = 0; n < 2; ++n)
            #pragma unroll
            for (int ks = 0; ks < 2; ++ks)
                b[n][ks] = FRAG(cur, 1, wn * 32 + n * 16 + fr, ks * 4 + kg);
        #pragma unroll
        for (int m = 0; m < 4; ++m)
            #pragma unroll
            for (int n = 0; n < 2; ++n)
                #pragma unroll
                for (int ks = 0; ks < 2; ++ks) {
                    acc[0][0][m][n] = __builtin_amdgcn_mfma_f32_16x16x32_bf16(af[0][m][ks], b[n][ks], acc[0][0][m][n], 0, 0, 0);
                    acc[1][0][m][n] = __builtin_amdgcn_mfma_f32_16x16x32_bf16(af[1][m][ks], b[n][ks], acc[1][0][m][n], 0, 0, 0);
                }
        #pragma unroll
        for (int n = 0; n < 2; ++n)
            #pragma unroll
            for (int ks = 0; ks < 2; ++ks)
                b[n][ks] = FRAG(cur, 1, 128 + wn * 32 + n * 16 + fr, ks * 4 + kg);
        #pragma unroll
        for (int m = 0; m < 4; ++m)
            #pragma unroll
            for (int n = 0; n < 2; ++n)
                #pragma unroll
                for (int ks = 0; ks < 2; ++ks) {
                    acc[1][1][m][n] = __builtin_amdgcn_mfma_f32_16x16x32_bf16(af[1][m][ks], b[n][ks], acc[1][1][m][n], 0, 0, 0);
                    acc[0][1][m][n] = __builtin_amdgcn_mfma_f32_16x16x32_bf16(af[0][m][ks], b[n][ks], acc[0][1][m][n], 0, 0, 0);
                }
    }

    // epilogue: C/D layout col=lane&15, row=(lane>>4)*4+j
    #pragma unroll
    for (int qm = 0; qm < 2; ++qm)
        #pragma unroll
        for (int qn = 0; qn < 2; ++qn)
            #pragma unroll
            for (int m = 0; m < 4; ++m)
                #pragma unroll
                for (int n = 0; n < 2; ++n) {
                    int rr = row0 + qm * 128 + wm * 64 + m * 16 + kg * 4;
                    int cc = col0 + qn * 128 + wn * 32 + n * 16 + fr;
                    #pragma unroll
                    for (int j = 0; j < 4; ++j)
                        C[(size_t)(rr + j) * NPIX + cc] = acc[qm][qn][m][n][j];
                }
#undef STAGE_A
#undef STAGE_B
#undef FRAG
}

// ---------------- Fallback path (workspace too small) ----------------
__global__ __launch_bounds__(256) void rgc_kernel(const float* __restrict__ x,
                                                  const float* __restrict__ act_on,
                                                  const float* __restrict__ act_off,
                                                  float* __restrict__ r) {
    unsigned f = blockIdx.x * 256u + threadIdx.x;     // float4 index
    unsigned n  = f >> 12;
    unsigned p4 = f & 4095u;
    float4 xv = reinterpret_cast<const float4*>(x)[p4];
    float4 a, o;
    if (n < 1024u) {
        a = reinterpret_cast<const float4*>(act_on)[(size_t)n * 4096u + p4];
        o.x = xv.x * a.x; o.y = xv.y * a.y; o.z = xv.z * a.z; o.w = xv.w * a.w;
    } else {
        a = reinterpret_cast<const float4*>(act_off)[(size_t)(n - 1024u) * 4096u + p4];
        o.x = (1.f - xv.x) * a.x; o.y = (1.f - xv.y) * a.y;
        o.z = (1.f - xv.z) * a.z; o.w = (1.f - xv.w) * a.w;
    }
    reinterpret_cast<float4*>(r)[f] = o;
}

__global__ __launch_bounds__(256) void lgn_kernel(const float* __restrict__ r,
                                                  const int* __restrict__ lgn_idx,
                                                  float* __restrict__ l) {
    unsigned f = blockIdx.x * 256u + threadIdx.x;
    unsigned k  = f >> 12;
    unsigned p4 = f & 4095u;
    unsigned src = (k < 2048u) ? k : (unsigned)lgn_idx[k - 2048u];
    reinterpret_cast<float4*>(l)[f] =
        reinterpret_cast<const float4*>(r)[(size_t)src * 4096u + p4];
}

__global__ __launch_bounds__(256) void gemm_fallback_kernel(const float* __restrict__ A,
                                                            const float* __restrict__ B,
                                                            float* __restrict__ C) {
    const int tid  = threadIdx.x;
    const int lane = tid & 63;
    const int wid  = tid >> 6;
    const int wr   = wid >> 1;
    const int wc   = wid & 1;
    const int row0 = blockIdx.y * 128;
    const int col0 = blockIdx.x * 128;

    __shared__ unsigned short As[4][128][8];
    __shared__ unsigned short Bs[4][128][8];

    f32x4 acc[4][4] = {};

    for (int k0 = 0; k0 < GK; k0 += 32) {
        #pragma unroll
        for (int i = 0; i < 4; ++i) {
            int f  = tid + 256 * i;
            int rr = f >> 3;
            int c4 = f & 7;
            float4 d = *reinterpret_cast<const float4*>(
                &A[(size_t)(row0 + rr) * GK + k0 + c4 * 4]);
            ushort4 s;
            s.x = f2b(d.x); s.y = f2b(d.y); s.z = f2b(d.z); s.w = f2b(d.w);
            *reinterpret_cast<ushort4*>(&As[c4 >> 1][rr][(c4 & 1) * 4]) = s;
        }
        #pragma unroll
        for (int i = 0; i < 4; ++i) {
            int f  = tid + 256 * i;
            int kk = f >> 5;
            int c4 = f & 31;
            float4 d = *reinterpret_cast<const float4*>(
                &B[(size_t)(k0 + kk) * NPIX + col0 + c4 * 4]);
            int g = kk >> 3, j = kk & 7;
            Bs[g][c4 * 4 + 0][j] = f2b(d.x);
            Bs[g][c4 * 4 + 1][j] = f2b(d.y);
            Bs[g][c4 * 4 + 2][j] = f2b(d.z);
            Bs[g][c4 * 4 + 3][j] = f2b(d.w);
        }
        __syncthreads();

        const int fr = lane & 15;
        const int kg = lane >> 4;
        bf16x8 af[4], bfr[4];
        #pragma unroll
        for (int m = 0; m < 4; ++m)
            af[m] = __builtin_bit_cast(bf16x8,
                *reinterpret_cast<const ushortx8*>(&As[kg][wr * 64 + m * 16 + fr][0]));
        #pragma unroll
        for (int n = 0; n < 4; ++n)
            bfr[n] = __builtin_bit_cast(bf16x8,
                *reinterpret_cast<const ushortx8*>(&Bs[kg][wc * 64 + n * 16 + fr][0]));
        #pragma unroll
        for (int m = 0; m < 4; ++m)
            #pragma unroll
            for (int n = 0; n < 4; ++n)
                acc[m][n] = __builtin_amdgcn_mfma_f32_16x16x32_bf16(af[m], bfr[n], acc[m][n], 0, 0, 0);
        __syncthreads();
    }

    #pragma unroll
    for (int m = 0; m < 4; ++m) {
        #pragma unroll
        for (int n = 0; n < 4; ++n) {
            int rr = row0 + wr * 64 + m * 16 + ((lane >> 4) << 2);
            int cc = col0 + wc * 64 + n * 16 + (lane & 15);
            #pragma unroll
            for (int j = 0; j < 4; ++j)
                C[(size_t)(rr + j) * NPIX + cc] = acc[m][n][j];
        }
    }
}

extern "C" void kernel_launch(void* const* d_in, const int* in_sizes, int n_in,
                              void* d_out, int out_size, void* d_ws, size_t ws_size,
                              hipStream_t stream) {
    const float* x       = (const float*)d_in[0];
    const float* act_on  = (const float*)d_in[1];
    const float* act_off = (const float*)d_in[2];
    const float* conn    = (const float*)d_in[3];
    const int*   lgn_idx = (const int*)d_in[4];

    float* out = (float*)d_out;
    float* r = out;                                    // [2048][16384]
    float* l = out + (size_t)NRROWS * NPIX;            // [5120][16384]
    float* v = out + (size_t)(NRROWS + NLROWS) * NPIX; // [4096][16384]

    const size_t lbt_bytes  = (size_t)NPIX * GK * sizeof(unsigned short);   // 167.8 MB
    const size_t conn_bytes = (size_t)NVROWS * GK * sizeof(unsigned short); //  41.9 MB

    if (ws_size >= lbt_bytes + conn_bytes) {
        unsigned short* lbt   = (unsigned short*)d_ws;
        unsigned short* connb = (unsigned short*)((char*)d_ws + lbt_bytes);
        // Fused stages 1+2: r + l + lbt in one pass (no r round-trip)
        dim3 tg(NPIX / 64, GK / 64);
        lgn_fused_kernel<<<tg, 256, 0, stream>>>(x, act_on, act_off, lgn_idx, r, l, lbt);
        // conn -> bf16
        cvt_conn_kernel<<<(NVROWS * GK / 4) / 256, 256, 0, stream>>>(conn, connb);
        // Stage 3: v = conn @ l  (256^2 single-sync MFMA)
        gemm8_kernel<<<(NVROWS / 256) * (NPIX / 256), 512, 0, stream>>>(connb, lbt, v);
    } else {
        rgc_kernel<<<(NRROWS * (NPIX / 4)) / 256, 256, 0, stream>>>(x, act_on, act_off, r);
        lgn_kernel<<<(NLROWS * (NPIX / 4)) / 256, 256, 0, stream>>>(r, lgn_idx, l);
        dim3 grid(NPIX / 128, NVROWS / 128);
        gemm_fallback_kernel<<<grid, 256, 0, stream>>>(conn, l, v);
    }
}

// Round 3
// 481.082 us; speedup vs baseline: 1.7519x; 1.7519x over previous
//
#include <hip/hip_runtime.h>
#include <hip/hip_bf16.h>

// Problem constants
#define NPIX   16384      // 128*128
#define NRROWS 2048       // r rows
#define NLROWS 5120       // l rows
#define NVROWS 4096       // v rows (= GEMM M)
#define GK     5120       // original K (fallback path)
#define KF     2048       // folded GEMM K  (lgn_idx only indexes [0,2048))
#define KEXTRA 3072       // duplicated LGN rows folded into conn
#define BK8    64         // GEMM K-step
#define NTF    (KF / BK8) // 32 K-tiles

using f32x4    = __attribute__((ext_vector_type(4))) float;
using bf16x8   = __attribute__((ext_vector_type(8))) __bf16;
using ushortx8 = __attribute__((ext_vector_type(8))) unsigned short;

// fp32 -> bf16 round-to-nearest-even (no NaN inputs in this problem)
__device__ __forceinline__ unsigned short f2b(float f) {
    union { float f; unsigned u; } v; v.f = f;
    unsigned r = (v.u + 0x7FFFu + ((v.u >> 16) & 1u)) >> 16;
    return (unsigned short)r;
}

#define GLOAD_LDS16(gsrc, ldst)                                                        \
    __builtin_amdgcn_global_load_lds(                                                  \
        (const __attribute__((address_space(1))) void*)(gsrc),                         \
        (__attribute__((address_space(3))) void*)(ldst), 16, 0, 0)

// ---------------- Fused stages 1+2: r, l = [r ; r[lgn_idx]], rbt = bf16(r)^T --------
// lgn_idx only indexes [0, 2048), so every l-row is recomputable directly from
// x/act_on/act_off (bit-exact vs computing r then gathering). The transposed bf16
// copy is only needed for the FIRST 2048 rows (GEMM K is folded to 2048).
__global__ __launch_bounds__(256) void lgn_fused_kernel(const float* __restrict__ x,
                                                        const float* __restrict__ act_on,
                                                        const float* __restrict__ act_off,
                                                        const int* __restrict__ lgn_idx,
                                                        float* __restrict__ r,
                                                        float* __restrict__ l,
                                                        unsigned short* __restrict__ rbt) {
    __shared__ unsigned short tile[64][66];
    const int k0 = blockIdx.y * 64;     // l-row tile base
    const int n0 = blockIdx.x * 64;     // pixel tile base
    const int t  = threadIdx.x;
    #pragma unroll
    for (int p = 0; p < 4; ++p) {
        int row = p * 16 + (t >> 4);
        int kk  = k0 + row;
        int src = (kk < NRROWS) ? kk : lgn_idx[kk - NRROWS];
        int c4  = t & 15;
        int px  = n0 + c4 * 4;
        float4 xv = *reinterpret_cast<const float4*>(&x[px]);
        float4 d;
        if (src < 1024) {
            float4 a = *reinterpret_cast<const float4*>(&act_on[(size_t)src * NPIX + px]);
            d.x = xv.x * a.x; d.y = xv.y * a.y; d.z = xv.z * a.z; d.w = xv.w * a.w;
        } else {
            float4 a = *reinterpret_cast<const float4*>(&act_off[(size_t)(src - 1024) * NPIX + px]);
            d.x = (1.f - xv.x) * a.x; d.y = (1.f - xv.y) * a.y;
            d.z = (1.f - xv.z) * a.z; d.w = (1.f - xv.w) * a.w;
        }
        *reinterpret_cast<float4*>(&l[(size_t)kk * NPIX + px]) = d;
        if (kk < NRROWS)
            *reinterpret_cast<float4*>(&r[(size_t)kk * NPIX + px]) = d;
        tile[row][c4 * 4 + 0] = f2b(d.x);
        tile[row][c4 * 4 + 1] = f2b(d.y);
        tile[row][c4 * 4 + 2] = f2b(d.z);
        tile[row][c4 * 4 + 3] = f2b(d.w);
    }
    if (k0 >= NRROWS) return;           // no transpose output needed for dup rows
    __syncthreads();
    #pragma unroll
    for (int p = 0; p < 4; ++p) {
        int nn = p * 16 + (t >> 4);     // output row (= pixel)
        int k4 = t & 15;
        ushort4 s;
        s.x = tile[k4 * 4 + 0][nn];
        s.y = tile[k4 * 4 + 1][nn];
        s.z = tile[k4 * 4 + 2][nn];
        s.w = tile[k4 * 4 + 3][nn];
        *reinterpret_cast<ushort4*>(&rbt[(size_t)(n0 + nn) * KF + k0 + k4 * 4]) = s;
    }
}

// ---------------- conn fold: Abf[m][i] = conn[m][i] + sum_{j:idx[j]=i} conn[m][2048+j]
// Exact K-reduction 5120 -> 2048: v = conn @ [r; r[idx]] == conn_folded @ r.
// conn >= 0, so the folded bf16 error bound equals the unfolded one.
__global__ __launch_bounds__(256) void fold_conn_kernel(const float* __restrict__ conn,
                                                        const int* __restrict__ lgn_idx,
                                                        unsigned short* __restrict__ Ab) {
    __shared__ float acc[KF];
    const int row = blockIdx.x;
    const int t   = threadIdx.x;
    const float* crow = conn + (size_t)row * GK;
    #pragma unroll
    for (int i = 0; i < KF / 256; ++i)
        acc[t + 256 * i] = crow[t + 256 * i];
    __syncthreads();
    #pragma unroll
    for (int j = 0; j < KEXTRA / 256; ++j) {
        int jj = t + 256 * j;
        float v = crow[KF + jj];
        atomicAdd(&acc[lgn_idx[jj]], v);
    }
    __syncthreads();
    #pragma unroll
    for (int i = 0; i < KF / 256; ++i) {
        int c = t + 256 * i;
        Ab[(size_t)row * KF + c] = f2b(acc[c]);
    }
}

// ---------------- Stage 3: v = conn_folded @ r — 256x256, BK=64, counted-vmcnt ----
// R1-proven schedule: 4 quadrant phases, staging spread 1 phase-pair ahead, and
// exactly 3 sync points per K-tile (vmcnt(4)+barrier at end-ph0/ph1/ph3) which
// publish A1(t), B1(t), A0B0(t+1) respectively. No mid-phase barriers: compiler
// emits counted lgkmcnt between ds_read and MFMA, waves drift between barriers.
__global__ __launch_bounds__(512, 2) void gemm8_kernel(const unsigned short* __restrict__ Ab, // conn_folded bf16 [4096][2048]
                                                       const unsigned short* __restrict__ Bb, // rbt [16384][2048]
                                                       float* __restrict__ C) {               // v [4096][16384]
    __shared__ unsigned short lds[2][2][256][64];   // [buf][A=0/B=1][row][col]

    const int tid  = threadIdx.x;
    const int lane = tid & 63;
    const int wid  = tid >> 6;
    const int wm   = wid >> 2;       // 0..1 : 64-row sub-block within each 128-quadrant
    const int wn   = wid & 3;        // 0..3 : 32-col sub-block within each 128-quadrant

    // XCD-aware bijective swizzle: 1024 wg, 8 XCDs, m-fast within XCD chunk.
    int bid = blockIdx.x;
    int swz = (bid & 7) * 128 + (bid >> 3);
    int mb  = swz & 15;
    int nb  = swz >> 4;
    const int row0 = mb * 256;
    const int col0 = nb * 256;

    // staging: STAGE(buf, rnd, kt) covers rows rnd*64 + (tid>>3); lane loads source
    // chunk gc = (lane&7) ^ (lane>>3)  (pre-swizzled global source; LDS dest linear)
    const int strow = tid >> 3;                 // 0..63
    const int gc    = (lane & 7) ^ (lane >> 3);

#define STAGE_A(buf, rnd, kt)                                                          \
    GLOAD_LDS16(&Ab[(size_t)(row0 + (rnd) * 64 + strow) * KF + (kt) * BK8 + gc * 8],   \
                &lds[buf][0][(rnd) * 64 + strow][(lane & 7) * 8])
#define STAGE_B(buf, rnd, kt)                                                          \
    GLOAD_LDS16(&Bb[(size_t)(col0 + (rnd) * 64 + strow) * KF + (kt) * BK8 + gc * 8],   \
                &lds[buf][1][(rnd) * 64 + strow][(lane & 7) * 8])

// swizzled fragment read: global chunk c of row lives at LDS chunk c^(row&7)
#define FRAG(buf, op, row, c)                                                          \
    __builtin_bit_cast(bf16x8, *reinterpret_cast<const ushortx8*>(                     \
        &lds[buf][op][row][(((c) ^ ((row) & 7)) * 8)]))

    f32x4 acc[2][2][4][2] = {};      // [qm][qn][m][n]
    const int fr = lane & 15;
    const int kg = lane >> 4;        // k-group: chunk = ks*4 + kg

    bf16x8 af[2][4][2];              // both A halves stay in registers
    bf16x8 b[2][2];                  // current B half

    // prologue: tile 0 -> buf 0, order A0,B0,A1,B1
    STAGE_A(0, 0, 0); STAGE_A(0, 1, 0);
    STAGE_B(0, 0, 0); STAGE_B(0, 1, 0);
    STAGE_A(0, 2, 0); STAGE_A(0, 3, 0);
    STAGE_B(0, 2, 0); STAGE_B(0, 3, 0);
    asm volatile("s_waitcnt vmcnt(4)" ::: "memory");   // A0,B0 landed
    __builtin_amdgcn_s_barrier();

    for (int t = 0; t < NTF - 1; ++t) {
        const int cur = t & 1;
        const int nxt = cur ^ 1;

        // ======== ph0: Q(0,0) — consume A0,B0 ========
        #pragma unroll
        for (int m = 0; m < 4; ++m)
            #pragma unroll
            for (int ks = 0; ks < 2; ++ks)
                af[0][m][ks] = FRAG(cur, 0, wm * 64 + m * 16 + fr, ks * 4 + kg);
        #pragma unroll
        for (int n = 0; n < 2; ++n)
            #pragma unroll
            for (int ks = 0; ks < 2; ++ks)
                b[n][ks] = FRAG(cur, 1, wn * 32 + n * 16 + fr, ks * 4 + kg);
        STAGE_A(nxt, 0, t + 1); STAGE_A(nxt, 1, t + 1);          // A0(t+1)
        __builtin_amdgcn_s_setprio(1);
        #pragma unroll
        for (int m = 0; m < 4; ++m)
            #pragma unroll
            for (int n = 0; n < 2; ++n)
                #pragma unroll
                for (int ks = 0; ks < 2; ++ks)
                    acc[0][0][m][n] = __builtin_amdgcn_mfma_f32_16x16x32_bf16(af[0][m][ks], b[n][ks], acc[0][0][m][n], 0, 0, 0);
        __builtin_amdgcn_s_setprio(0);
        asm volatile("s_waitcnt vmcnt(4)" ::: "memory");         // A1(t) landed
        __builtin_amdgcn_s_barrier();                            // publish A1(t)

        // ======== ph1: Q(1,0) — consume A1 (B0 in regs) ========
        #pragma unroll
        for (int m = 0; m < 4; ++m)
            #pragma unroll
            for (int ks = 0; ks < 2; ++ks)
                af[1][m][ks] = FRAG(cur, 0, 128 + wm * 64 + m * 16 + fr, ks * 4 + kg);
        STAGE_B(nxt, 0, t + 1); STAGE_B(nxt, 1, t + 1);          // B0(t+1)
        __builtin_amdgcn_s_setprio(1);
        #pragma unroll
        for (int m = 0; m < 4; ++m)
            #pragma unroll
            for (int n = 0; n < 2; ++n)
                #pragma unroll
                for (int ks = 0; ks < 2; ++ks)
                    acc[1][0][m][n] = __builtin_amdgcn_mfma_f32_16x16x32_bf16(af[1][m][ks], b[n][ks], acc[1][0][m][n], 0, 0, 0);
        __builtin_amdgcn_s_setprio(0);
        asm volatile("s_waitcnt vmcnt(4)" ::: "memory");         // B1(t) landed
        __builtin_amdgcn_s_barrier();                            // publish B1(t)

        // ======== ph2: Q(1,1) — consume B1 (A1 in regs) ========
        #pragma unroll
        for (int n = 0; n < 2; ++n)
            #pragma unroll
            for (int ks = 0; ks < 2; ++ks)
                b[n][ks] = FRAG(cur, 1, 128 + wn * 32 + n * 16 + fr, ks * 4 + kg);
        STAGE_A(nxt, 2, t + 1); STAGE_A(nxt, 3, t + 1);          // A1(t+1)
        __builtin_amdgcn_s_setprio(1);
        #pragma unroll
        for (int m = 0; m < 4; ++m)
            #pragma unroll
            for (int n = 0; n < 2; ++n)
                #pragma unroll
                for (int ks = 0; ks < 2; ++ks)
                    acc[1][1][m][n] = __builtin_amdgcn_mfma_f32_16x16x32_bf16(af[1][m][ks], b[n][ks], acc[1][1][m][n], 0, 0, 0);
        __builtin_amdgcn_s_setprio(0);
        // no barrier: ph3 is pure-reg; B1(t+1) staging targets tile t-1's region,
        // whose last readers were synced at the end-ph3(t-1) barrier.

        // ======== ph3: Q(0,1) — pure-reg (A0, B1) ========
        STAGE_B(nxt, 2, t + 1); STAGE_B(nxt, 3, t + 1);          // B1(t+1)
        __builtin_amdgcn_s_setprio(1);
        #pragma unroll
        for (int m = 0; m < 4; ++m)
            #pragma unroll
            for (int n = 0; n < 2; ++n)
                #pragma unroll
                for (int ks = 0; ks < 2; ++ks)
                    acc[0][1][m][n] = __builtin_amdgcn_mfma_f32_16x16x32_bf16(af[0][m][ks], b[n][ks], acc[0][1][m][n], 0, 0, 0);
        __builtin_amdgcn_s_setprio(0);
        asm volatile("s_waitcnt vmcnt(4)" ::: "memory");         // A0,B0(t+1) landed
        __builtin_amdgcn_s_barrier();                            // publish A0,B0(t+1)
    }

    // ======== epilogue tile NTF-1 (no staging) ========
    {
        asm volatile("s_waitcnt vmcnt(0)" ::: "memory");
        __builtin_amdgcn_s_barrier();
        const int cur = (NTF - 1) & 1;
        #pragma unroll
        for (int m = 0; m < 4; ++m)
            #pragma unroll
            for (int ks = 0; ks < 2; ++ks) {
                af[0][m][ks] = FRAG(cur, 0, wm * 64 + m * 16 + fr, ks * 4 + kg);
                af[1][m][ks] = FRAG(cur, 0, 128 + wm * 64 + m * 16 + fr, ks * 4 + kg);
            }
        #pragma unroll
        for (int n = 0; n < 2; ++n)
            #pragma unroll
            for (int ks = 0; ks < 2; ++ks)
                b[n][ks] = FRAG(cur, 1, wn * 32 + n * 16 + fr, ks * 4 + kg);
        #pragma unroll
        for (int m = 0; m < 4; ++m)
            #pragma unroll
            for (int n = 0; n < 2; ++n)
                #pragma unroll
                for (int ks = 0; ks < 2; ++ks) {
                    acc[0][0][m][n] = __builtin_amdgcn_mfma_f32_16x16x32_bf16(af[0][m][ks], b[n][ks], acc[0][0][m][n], 0, 0, 0);
                    acc[1][0][m][n] = __builtin_amdgcn_mfma_f32_16x16x32_bf16(af[1][m][ks], b[n][ks], acc[1][0][m][n], 0, 0, 0);
                }
        #pragma unroll
        for (int n = 0; n < 2; ++n)
            #pragma unroll
            for (int ks = 0; ks < 2; ++ks)
                b[n][ks] = FRAG(cur, 1, 128 + wn * 32 + n * 16 + fr, ks * 4 + kg);
        #pragma unroll
        for (int m = 0; m < 4; ++m)
            #pragma unroll
            for (int n = 0; n < 2; ++n)
                #pragma unroll
                for (int ks = 0; ks < 2; ++ks) {
                    acc[1][1][m][n] = __builtin_amdgcn_mfma_f32_16x16x32_bf16(af[1][m][ks], b[n][ks], acc[1][1][m][n], 0, 0, 0);
                    acc[0][1][m][n] = __builtin_amdgcn_mfma_f32_16x16x32_bf16(af[0][m][ks], b[n][ks], acc[0][1][m][n], 0, 0, 0);
                }
    }

    // epilogue: C/D layout col=lane&15, row=(lane>>4)*4+j
    #pragma unroll
    for (int qm = 0; qm < 2; ++qm)
        #pragma unroll
        for (int qn = 0; qn < 2; ++qn)
            #pragma unroll
            for (int m = 0; m < 4; ++m)
                #pragma unroll
                for (int n = 0; n < 2; ++n) {
                    int rr = row0 + qm * 128 + wm * 64 + m * 16 + kg * 4;
                    int cc = col0 + qn * 128 + wn * 32 + n * 16 + fr;
                    #pragma unroll
                    for (int j = 0; j < 4; ++j)
                        C[(size_t)(rr + j) * NPIX + cc] = acc[qm][qn][m][n][j];
                }
#undef STAGE_A
#undef STAGE_B
#undef FRAG
}

// ---------------- Fallback path (workspace too small) ----------------
__global__ __launch_bounds__(256) void rgc_kernel(const float* __restrict__ x,
                                                  const float* __restrict__ act_on,
                                                  const float* __restrict__ act_off,
                                                  float* __restrict__ r) {
    unsigned f = blockIdx.x * 256u + threadIdx.x;     // float4 index
    unsigned n  = f >> 12;
    unsigned p4 = f & 4095u;
    float4 xv = reinterpret_cast<const float4*>(x)[p4];
    float4 a, o;
    if (n < 1024u) {
        a = reinterpret_cast<const float4*>(act_on)[(size_t)n * 4096u + p4];
        o.x = xv.x * a.x; o.y = xv.y * a.y; o.z = xv.z * a.z; o.w = xv.w * a.w;
    } else {
        a = reinterpret_cast<const float4*>(act_off)[(size_t)(n - 1024u) * 4096u + p4];
        o.x = (1.f - xv.x) * a.x; o.y = (1.f - xv.y) * a.y;
        o.z = (1.f - xv.z) * a.z; o.w = (1.f - xv.w) * a.w;
    }
    reinterpret_cast<float4*>(r)[f] = o;
}

__global__ __launch_bounds__(256) void lgn_kernel(const float* __restrict__ r,
                                                  const int* __restrict__ lgn_idx,
                                                  float* __restrict__ l) {
    unsigned f = blockIdx.x * 256u + threadIdx.x;
    unsigned k  = f >> 12;
    unsigned p4 = f & 4095u;
    unsigned src = (k < 2048u) ? k : (unsigned)lgn_idx[k - 2048u];
    reinterpret_cast<float4*>(l)[f] =
        reinterpret_cast<const float4*>(r)[(size_t)src * 4096u + p4];
}

__global__ __launch_bounds__(256) void gemm_fallback_kernel(const float* __restrict__ A,
                                                            const float* __restrict__ B,
                                                            float* __restrict__ C) {
    const int tid  = threadIdx.x;
    const int lane = tid & 63;
    const int wid  = tid >> 6;
    const int wr   = wid >> 1;
    const int wc   = wid & 1;
    const int row0 = blockIdx.y * 128;
    const int col0 = blockIdx.x * 128;

    __shared__ unsigned short As[4][128][8];
    __shared__ unsigned short Bs[4][128][8];

    f32x4 acc[4][4] = {};

    for (int k0 = 0; k0 < GK; k0 += 32) {
        #pragma unroll
        for (int i = 0; i < 4; ++i) {
            int f  = tid + 256 * i;
            int rr = f >> 3;
            int c4 = f & 7;
            float4 d = *reinterpret_cast<const float4*>(
                &A[(size_t)(row0 + rr) * GK + k0 + c4 * 4]);
            ushort4 s;
            s.x = f2b(d.x); s.y = f2b(d.y); s.z = f2b(d.z); s.w = f2b(d.w);
            *reinterpret_cast<ushort4*>(&As[c4 >> 1][rr][(c4 & 1) * 4]) = s;
        }
        #pragma unroll
        for (int i = 0; i < 4; ++i) {
            int f  = tid + 256 * i;
            int kk = f >> 5;
            int c4 = f & 31;
            float4 d = *reinterpret_cast<const float4*>(
                &B[(size_t)(k0 + kk) * NPIX + col0 + c4 * 4]);
            int g = kk >> 3, j = kk & 7;
            Bs[g][c4 * 4 + 0][j] = f2b(d.x);
            Bs[g][c4 * 4 + 1][j] = f2b(d.y);
            Bs[g][c4 * 4 + 2][j] = f2b(d.z);
            Bs[g][c4 * 4 + 3][j] = f2b(d.w);
        }
        __syncthreads();

        const int fr = lane & 15;
        const int kg = lane >> 4;
        bf16x8 af[4], bfr[4];
        #pragma unroll
        for (int m = 0; m < 4; ++m)
            af[m] = __builtin_bit_cast(bf16x8,
                *reinterpret_cast<const ushortx8*>(&As[kg][wr * 64 + m * 16 + fr][0]));
        #pragma unroll
        for (int n = 0; n < 4; ++n)
            bfr[n] = __builtin_bit_cast(bf16x8,
                *reinterpret_cast<const ushortx8*>(&Bs[kg][wc * 64 + n * 16 + fr][0]));
        #pragma unroll
        for (int m = 0; m < 4; ++m)
            #pragma unroll
            for (int n = 0; n < 4; ++n)
                acc[m][n] = __builtin_amdgcn_mfma_f32_16x16x32_bf16(af[m], bfr[n], acc[m][n], 0, 0, 0);
        __syncthreads();
    }

    #pragma unroll
    for (int m = 0; m < 4; ++m) {
        #pragma unroll
        for (int n = 0; n < 4; ++n) {
            int rr = row0 + wr * 64 + m * 16 + ((lane >> 4) << 2);
            int cc = col0 + wc * 64 + n * 16 + (lane & 15);
            #pragma unroll
            for (int j = 0; j < 4; ++j)
                C[(size_t)(rr + j) * NPIX + cc] = acc[m][n][j];
        }
    }
}

extern "C" void kernel_launch(void* const* d_in, const int* in_sizes, int n_in,
                              void* d_out, int out_size, void* d_ws, size_t ws_size,
                              hipStream_t stream) {
    const float* x       = (const float*)d_in[0];
    const float* act_on  = (const float*)d_in[1];
    const float* act_off = (const float*)d_in[2];
    const float* conn    = (const float*)d_in[3];
    const int*   lgn_idx = (const int*)d_in[4];

    float* out = (float*)d_out;
    float* r = out;                                    // [2048][16384]
    float* l = out + (size_t)NRROWS * NPIX;            // [5120][16384]
    float* v = out + (size_t)(NRROWS + NLROWS) * NPIX; // [4096][16384]

    const size_t rbt_bytes  = (size_t)NPIX * KF * sizeof(unsigned short);   // 67.1 MB
    const size_t conn_bytes = (size_t)NVROWS * KF * sizeof(unsigned short); // 16.8 MB

    if (ws_size >= rbt_bytes + conn_bytes) {
        unsigned short* rbt   = (unsigned short*)d_ws;
        unsigned short* connb = (unsigned short*)((char*)d_ws + rbt_bytes);
        // Fused stages 1+2: r + l + rbt (bf16 r^T) in one pass
        dim3 tg(NPIX / 64, NLROWS / 64);
        lgn_fused_kernel<<<tg, 256, 0, stream>>>(x, act_on, act_off, lgn_idx, r, l, rbt);
        // conn fold: K 5120 -> 2048 (exact column scatter-add), fp32 acc, bf16 out
        fold_conn_kernel<<<NVROWS, 256, 0, stream>>>(conn, lgn_idx, connb);
        // Stage 3: v = conn_folded @ r  (256^2 counted-vmcnt MFMA, K=2048)
        gemm8_kernel<<<(NVROWS / 256) * (NPIX / 256), 512, 0, stream>>>(connb, rbt, v);
    } else {
        rgc_kernel<<<(NRROWS * (NPIX / 4)) / 256, 256, 0, stream>>>(x, act_on, act_off, r);
        lgn_kernel<<<(NLROWS * (NPIX / 4)) / 256, 256, 0, stream>>>(r, lgn_idx, l);
        dim3 grid(NPIX / 128, NVROWS / 128);
        gemm_fallback_kernel<<<grid, 256, 0, stream>>>(conn, l, v);
    }
}